// Round 1
// baseline (511.257 us; speedup 1.0000x reference)
//
#include <hip/hip_runtime.h>
#include <math.h>

// 2-layer ReLU RNN, B=256, T=1000 (input 800 + zero pad), H=128, F=5.
// R16: wave-concentration rewrite of R15. 768thr/12 waves -> 256thr/4 waves:
//   wave0 = h0 engine (Whh0 + x-dot), wave1 = A engine (Wih1),
//   wave2 = h1 engine (Whh1), wave3 = y-dots (every 16 steps) only.
// Each engine wave holds its FULL 128x128 fp16 weight matrix in registers
// (wp[8][16] = 128 VGPRs/lane); lanes = 4 col-chunks(32) x 16 row-groups(8);
// XOR-linear row map g=4*(c&1)+2*((c>>1)&1) -> 2-level DPP butterfly leaves
// each lane with a CONTIGUOUS row pair (base, base+1): packed h16x2 LDS
// writes, float2 A writes, no writer masks. Per-SIMD per-step VALU issue
// drops ~690 -> ~310 cyc (the 12-wave convoy was the measured bottleneck:
// VALUBusy 62% x 1117cyc step). Same pipeline skew + ring + y cadence as R15.

#define TT    1000
#define TIN   800
#define HD    128
#define NF    5
#define BATCH 256

typedef _Float16 h16x2 __attribute__((ext_vector_type(2)));
typedef _Float16 h16x8 __attribute__((ext_vector_type(8)));

template<int CTRL>
__device__ __forceinline__ float dpp_mov(float v) {
    union { float f; int i; } u, r;
    u.f = v;
    r.i = __builtin_amdgcn_update_dpp(0, u.i, CTRL, 0xF, 0xF, true);
    return r.f;
}

__global__ __launch_bounds__(256, 1) void rnn_w4(
    const float* __restrict__ x,        // [256,800,5]
    const float* __restrict__ h_state,  // [2,256,128]
    const float* __restrict__ w_ih0,    // [128,5]
    const float* __restrict__ w_hh0,    // [128,128]
    const float* __restrict__ b_ih0,    // [128]
    const float* __restrict__ b_hh0,    // [128]
    const float* __restrict__ w_ih1,    // [128,128]
    const float* __restrict__ w_hh1,    // [128,128]
    const float* __restrict__ b_ih1,    // [128]
    const float* __restrict__ b_hh1,    // [128]
    const float* __restrict__ w_out,    // [1,128]
    const float* __restrict__ b_out,    // [1]
    float* __restrict__ out)            // [204800 y] ++ [65536 final states]
{
    __shared__ __align__(16) _Float16 x_h[TIN * 8];      // fp16, 12.8 KB
    __shared__ __align__(16) _Float16 h0h[2][HD];
    __shared__ __align__(16) float A_f[2][HD];           // fp32 pre-act
    __shared__ __align__(16) _Float16 ring[32][HD];      // h1 state+history
    __shared__ float y_lds[TIN];

    const int tid  = threadIdx.x;
    const int bb   = blockIdx.x;
    const int wv   = tid >> 6;          // wave id 0..3 (engine id)
    const int lane = tid & 63;
    const int c    = lane & 3;          // col chunk (32 cols each)
    const int rg   = lane >> 2;         // row group (8 rows)
    const int g    = 4 * (c & 1) + 2 * ((c >> 1) & 1);   // XOR-linear row map
    const int base = rg * 8 + g;        // this lane finalizes rows base, base+1

    // ---- stage x[bb] into LDS (fp16, stride 8, pads zero) ----
    for (int i = tid; i < TIN * 8; i += 256) x_h[i] = (_Float16)0.f;
    __syncthreads();
    for (int i = tid; i < TIN * NF; i += 256) {
        int t = i / 5, f = i - 5 * t;
        x_h[t * 8 + f] = (_Float16)x[bb * (TIN * NF) + i];
    }
    if (tid < HD) {
        h0h[0][tid]   = (_Float16)h_state[bb * HD + tid];
        ring[31][tid] = (_Float16)h_state[BATCH * HD + bb * HD + tid];  // h1[-1]
    }

    // ---- weights: full matrix per engine wave, 8 rows x 32 cols per lane ----
    // wp[j][t]: row rg*8+(j^g), cols c*32+2t .. +1  (fp16 pairs, 128 VGPRs)
    h16x2 wp[8][16];
    if (wv < 3) {
        const float* Wsrc = (wv == 0) ? w_hh0 : ((wv == 1) ? w_ih1 : w_hh1);
        #pragma unroll
        for (int j = 0; j < 8; ++j) {
            const float* rp = Wsrc + (rg * 8 + (j ^ g)) * HD + c * 32;
            #pragma unroll
            for (int t = 0; t < 16; ++t) {
                h16x2 w2 = { (_Float16)rp[2 * t], (_Float16)rp[2 * t + 1] };
                wp[j][t] = w2;
            }
        }
    }

    h16x2 wxa[3], wxb[3];               // wave0: Wih0 rows base, base+1
    h16x2 wo[16];                       // wave3: wout cols c*32..+31
    float bias0 = 0.f, bias1 = 0.f;
    if (wv == 0) {
        #pragma unroll
        for (int k = 0; k < 3; ++k) {
            _Float16 a0 = (_Float16)w_ih0[base * NF + 2 * k];
            _Float16 a1 = (2 * k + 1 < NF) ? (_Float16)w_ih0[base * NF + 2 * k + 1] : (_Float16)0.f;
            _Float16 b0 = (_Float16)w_ih0[(base + 1) * NF + 2 * k];
            _Float16 b1 = (2 * k + 1 < NF) ? (_Float16)w_ih0[(base + 1) * NF + 2 * k + 1] : (_Float16)0.f;
            h16x2 wa = { a0, a1 }; wxa[k] = wa;
            h16x2 wb = { b0, b1 }; wxb[k] = wb;
        }
        bias0 = b_ih0[base] + b_hh0[base];
        bias1 = b_ih0[base + 1] + b_hh0[base + 1];
    } else if (wv == 2) {
        bias0 = b_ih1[base] + b_hh1[base];
        bias1 = b_ih1[base + 1] + b_hh1[base + 1];
    } else if (wv == 3) {
        #pragma unroll
        for (int t = 0; t < 16; ++t) {
            h16x2 w2 = { (_Float16)w_out[c * 32 + 2 * t],
                         (_Float16)w_out[c * 32 + 2 * t + 1] };
            wo[t] = w2;
        }
    }
    const float bout = b_out[0];

    float hfin0 = 0.f, hfin1 = 0.f;

    __syncthreads();

    // 128x128 matvec on ONE wave: 128 fdot2/lane + 2-level DPP butterfly.
    // Returns full sums for rows base (r0) and base+1 (r1).
    auto matvec = [&](const _Float16* hbuf, float& r0, float& r1) {
        h16x8 hv[4];
        #pragma unroll
        for (int u2 = 0; u2 < 4; ++u2)
            hv[u2] = *(const h16x8*)(hbuf + c * 32 + 8 * u2);
        float a[8];
        #pragma unroll
        for (int j = 0; j < 8; ++j) {
            float aj = 0.f;
            #pragma unroll
            for (int u2 = 0; u2 < 4; ++u2) {
                h16x2 hp0 = { hv[u2][0], hv[u2][1] };
                h16x2 hp1 = { hv[u2][2], hv[u2][3] };
                h16x2 hp2 = { hv[u2][4], hv[u2][5] };
                h16x2 hp3 = { hv[u2][6], hv[u2][7] };
                aj = __builtin_amdgcn_fdot2(wp[j][4 * u2 + 0], hp0, aj, false);
                aj = __builtin_amdgcn_fdot2(wp[j][4 * u2 + 1], hp1, aj, false);
                aj = __builtin_amdgcn_fdot2(wp[j][4 * u2 + 2], hp2, aj, false);
                aj = __builtin_amdgcn_fdot2(wp[j][4 * u2 + 3], hp3, aj, false);
            }
            a[j] = aj;
        }
        // level1: lane xor1 (g^=4): partner a[j^4] is my row j^g's other half
        a[0] += dpp_mov<0xB1>(a[4]);
        a[1] += dpp_mov<0xB1>(a[5]);
        a[2] += dpp_mov<0xB1>(a[6]);
        a[3] += dpp_mov<0xB1>(a[7]);
        // level2: lane xor2 (g^=2)
        a[0] += dpp_mov<0x4E>(a[2]);
        a[1] += dpp_mov<0x4E>(a[3]);
        r0 = a[0];      // row base
        r1 = a[1];      // row base+1
    };

    #pragma unroll 2
    for (int s = 0; s < TT + 2; ++s) {
        const int p = s & 1;
        const int q = p ^ 1;

        if (wv == 0) {
            // h0[s] = relu(Whh0.h0[s-1] + Wih0.x[s] + b)
            if (s < TT) {
                float v0, v1;
                matvec(h0h[p], v0, v1);
                v0 += bias0; v1 += bias1;
                if (s < TIN) {      // uniform branch
                    h16x8 xv = *(const h16x8*)(&x_h[s * 8]);
                    h16x2 xp0 = { xv[0], xv[1] };
                    h16x2 xp1 = { xv[2], xv[3] };
                    h16x2 xp2 = { xv[4], xv[5] };   // slot 5 is zero pad
                    float xc0 = __builtin_amdgcn_fdot2(wxa[2], xp2, 0.f, false);
                    xc0 = __builtin_amdgcn_fdot2(wxa[1], xp1, xc0, false);
                    xc0 = __builtin_amdgcn_fdot2(wxa[0], xp0, xc0, false);
                    float xc1 = __builtin_amdgcn_fdot2(wxb[2], xp2, 0.f, false);
                    xc1 = __builtin_amdgcn_fdot2(wxb[1], xp1, xc1, false);
                    xc1 = __builtin_amdgcn_fdot2(wxb[0], xp0, xc1, false);
                    v0 += xc0; v1 += xc1;
                }
                v0 = fmaxf(v0, 0.f);
                v1 = fmaxf(v1, 0.f);
                h16x2 hv = { (_Float16)v0, (_Float16)v1 };
                *(h16x2*)(&h0h[q][base]) = hv;
                if (s == TT - 1) { hfin0 = v0; hfin1 = v1; }
            }
        } else if (wv == 1) {
            // A[s-1] = Wih1 . h0[s-1]  (fp32)
            if (s <= TT) {
                float v0, v1;
                matvec(h0h[p], v0, v1);
                *(float2*)(&A_f[q][base]) = make_float2(v0, v1);
            }
        } else if (wv == 2) {
            // h1[s-2] = relu(A[s-2] + Whh1.h1[s-3] + b); h1 lives in ring
            if (s >= 2) {
                const int u = s - 2;
                float v0, v1;
                matvec(&ring[(u + 31) & 31][0], v0, v1);
                float2 av = *(const float2*)(&A_f[p][base]);
                v0 = fmaxf(v0 + bias0 + av.x, 0.f);
                v1 = fmaxf(v1 + bias1 + av.y, 0.f);
                h16x2 hv = { (_Float16)v0, (_Float16)v1 };
                *(h16x2*)(&ring[u & 31][base]) = hv;
                if (u == TT - 1) { hfin0 = v0; hfin1 = v1; }
            }
        } else {
            // y-dots every 16 steps: 16 slots x 4 lanes, DPP-only reduce
            if (s >= 18 && s <= 818 && ((s - 2) & 15) == 0) {
                const int slot = lane >> 2;
                const int u    = (s - 33) + slot;
                if (u >= 0 && u < TIN) {
                    const _Float16* rb = &ring[u & 31][0] + c * 32;
                    float z = 0.f;
                    #pragma unroll
                    for (int u2 = 0; u2 < 4; ++u2) {
                        h16x8 hv = *(const h16x8*)(rb + 8 * u2);
                        h16x2 hp0 = { hv[0], hv[1] };
                        h16x2 hp1 = { hv[2], hv[3] };
                        h16x2 hp2 = { hv[4], hv[5] };
                        h16x2 hp3 = { hv[6], hv[7] };
                        z = __builtin_amdgcn_fdot2(wo[4 * u2 + 0], hp0, z, false);
                        z = __builtin_amdgcn_fdot2(wo[4 * u2 + 1], hp1, z, false);
                        z = __builtin_amdgcn_fdot2(wo[4 * u2 + 2], hp2, z, false);
                        z = __builtin_amdgcn_fdot2(wo[4 * u2 + 3], hp3, z, false);
                    }
                    z += dpp_mov<0xB1>(z);    // xor1 (within quad = same slot)
                    z += dpp_mov<0x4E>(z);    // xor2
                    if (c == 0) y_lds[u] = 1.f / (1.f + expf(-(z + bout)));
                }
            }
        }
        __syncthreads();
    }

    // ---- epilogue: single global dump ----
    for (int i = tid; i < TIN; i += 256)
        out[bb * TIN + i] = y_lds[i];
    if (wv == 0)
        *(float2*)(&out[TIN * BATCH + bb * HD + base]) = make_float2(hfin0, hfin1);
    if (wv == 2)
        *(float2*)(&out[TIN * BATCH + BATCH * HD + bb * HD + base]) = make_float2(hfin0, hfin1);
}

extern "C" void kernel_launch(void* const* d_in, const int* in_sizes, int n_in,
                              void* d_out, int out_size, void* d_ws, size_t ws_size,
                              hipStream_t stream) {
    (void)in_sizes; (void)n_in; (void)d_ws; (void)ws_size; (void)out_size;
    rnn_w4<<<dim3(BATCH), dim3(256), 0, stream>>>(
        (const float*)d_in[0],  (const float*)d_in[1],
        (const float*)d_in[2],  (const float*)d_in[3],
        (const float*)d_in[4],  (const float*)d_in[5],
        (const float*)d_in[6],  (const float*)d_in[7],
        (const float*)d_in[8],  (const float*)d_in[9],
        (const float*)d_in[10], (const float*)d_in[11],
        (float*)d_out);
}